// Round 9
// baseline (446.846 us; speedup 1.0000x reference)
//
#include <hip/hip_runtime.h>
#include <stdint.h>
#include <stddef.h>

// Shapes: D=512, F=2048, H=8, L=128, B=4
#define NTOK 512      // B*L tokens
#define NM   65536    // B*L*L edge rows

typedef __bf16 bf16x8 __attribute__((ext_vector_type(8)));
typedef float  f32x4  __attribute__((ext_vector_type(4)));
typedef unsigned int u32x4 __attribute__((ext_vector_type(4)));

__device__ __forceinline__ unsigned short f2bf(float f) {
    unsigned int u = __builtin_bit_cast(unsigned int, f);
    u += 0x7FFFu + ((u >> 16) & 1u);
    return (unsigned short)(u >> 16);
}
__device__ __forceinline__ float bf2f(unsigned short s) {
    unsigned int u = ((unsigned int)s) << 16;
    return __builtin_bit_cast(float, u);
}

// async global->LDS, 16B per lane; LDS dest is wave-uniform base + lane*16
__device__ __forceinline__ void gload16(const void* g, void* l) {
    __builtin_amdgcn_global_load_lds(
        (const __attribute__((address_space(1))) void*)g,
        (__attribute__((address_space(3))) void*)l,
        16, 0, 0);
}

// ---------- transpose h (L,B,D) -> Qm token-major bf16 (b*128+i, 512) ----------
__global__ __launch_bounds__(256) void k_qtrans(const float* __restrict__ h,
                                                unsigned short* __restrict__ Qm) {
    int idx = blockIdx.x * 256 + threadIdx.x;   // 262144 total
    int tok = idx >> 9, d = idx & 511;
    int b = tok >> 7, i = tok & 127;
    Qm[idx] = f2bf(h[(i * 4 + b) * 512 + d]);
}

// ---------- merged LDS-tiled fp32 -> bf16 transposes (job table) ----------
struct TRJob { const float* src; unsigned short* dst; int srcLd, dstLd, tcols; float scale; };
struct TRJobs { TRJob j[11]; int start[12]; };

__global__ __launch_bounds__(256) void k_trN(TRJobs js) {
    __shared__ float tile[64][65];
    int b = blockIdx.x;
    int ji = 0;
    while (ji < 10 && b >= js.start[ji + 1]) ++ji;
    TRJob jb = js.j[ji];
    int rel = b - js.start[ji];
    int bx = rel % jb.tcols, by = rel / jb.tcols;
    int r0 = by * 64, c0 = bx * 64;
    int t = threadIdx.x;
    int c = t & 63, rr = t >> 6;                // rr in 0..3
    #pragma unroll
    for (int ii = 0; ii < 16; ++ii) {
        int r = ii * 4 + rr;
        tile[r][c] = jb.src[(size_t)(r0 + r) * jb.srcLd + c0 + c];
    }
    __syncthreads();
    #pragma unroll
    for (int ii = 0; ii < 16; ++ii) {
        int n = ii * 4 + rr;                    // local col of src = row of dst
        jb.dst[(size_t)(c0 + n) * jb.dstLd + r0 + c] = f2bf(tile[c][n] * jb.scale);
    }
}

// ---------- kwT fp32 + concat bias1 ----------
__global__ __launch_bounds__(256) void k_kwT(const float* __restrict__ kw,
                                             float* __restrict__ kwT) {
    int idx = blockIdx.x * 256 + threadIdx.x;   // 262144
    kwT[idx] = kw[(size_t)(idx & 511) * 512 + (idx >> 9)];
}
__global__ __launch_bounds__(256) void k_bias1(const float* __restrict__ Wob,
                                               const float* __restrict__ Wib,
                                               const float* __restrict__ qb,
                                               float* __restrict__ bias1) {
    int i = blockIdx.x * 256 + threadIdx.x;     // 2560
    if (i >= 2560) return;
    float v = 0.f;
    if (i < 512) v = Wob[i];
    else if (i < 1024) v = 0.f;
    else if (i < 1536) v = Wib[i - 1024];
    else if (i < 2048) v = 0.f;
    else v = qb[i - 2048] * 0.125f;
    bias1[i] = v;
}

// ---------- generic bf16 MFMA GEMM: out = relu(A@B^T + bias) [+accs] ----------
struct MMP {
    const unsigned short* A;  int lda;
    const unsigned short* Bt; int ldb;
    const float* bias;
    const float* accs;
    float* outF;
    unsigned short* outB;
    int ldo;
    int K;
    int relu;
    int aOffPerN64;
    int zKOff;
    int zOutOff;
};

__global__ __launch_bounds__(256) void k_mm(MMP p) {
    __shared__ unsigned char As[64 * 128];
    __shared__ unsigned char Bs[64 * 128];
    int t = threadIdx.x;
    int lane = t & 63, w = t >> 6;
    int m0 = blockIdx.x * 64, n0 = blockIdx.y * 64;
    int z = blockIdx.z;
    const unsigned short* A  = p.A + (size_t)(n0 >> 6) * p.aOffPerN64 + (size_t)z * p.zKOff;
    const unsigned short* Bt = p.Bt + (size_t)z * p.zKOff;
    int wm = (w >> 1) * 32, wn = (w & 1) * 32;
    f32x4 acc[2][2];
    #pragma unroll
    for (int a = 0; a < 2; ++a)
        #pragma unroll
        for (int b = 0; b < 2; ++b) acc[a][b] = (f32x4){0.f, 0.f, 0.f, 0.f};

    for (int kb = 0; kb < p.K; kb += 64) {
        __syncthreads();
        #pragma unroll
        for (int s = 0; s < 2; ++s) {
            int c = t + s * 256;
            int r = c >> 3, kc = (c & 7) * 8;
            int off = (r * 128 + kc * 2) ^ ((r & 7) << 4);
            *reinterpret_cast<u32x4*>(As + off) =
                *reinterpret_cast<const u32x4*>(A + (size_t)(m0 + r) * p.lda + kb + kc);
            *reinterpret_cast<u32x4*>(Bs + off) =
                *reinterpret_cast<const u32x4*>(Bt + (size_t)(n0 + r) * p.ldb + kb + kc);
        }
        __syncthreads();
        #pragma unroll
        for (int kh = 0; kh < 2; ++kh) {
            int kk = kh * 32 + (lane >> 4) * 8;
            bf16x8 af[2], bfr[2];
            #pragma unroll
            for (int mf = 0; mf < 2; ++mf) {
                int r = wm + mf * 16 + (lane & 15);
                int off = (r * 128 + kk * 2) ^ ((r & 7) << 4);
                af[mf] = *reinterpret_cast<const bf16x8*>(As + off);
            }
            #pragma unroll
            for (int nf = 0; nf < 2; ++nf) {
                int r = wn + nf * 16 + (lane & 15);
                int off = (r * 128 + kk * 2) ^ ((r & 7) << 4);
                bfr[nf] = *reinterpret_cast<const bf16x8*>(Bs + off);
            }
            #pragma unroll
            for (int mf = 0; mf < 2; ++mf)
                #pragma unroll
                for (int nf = 0; nf < 2; ++nf)
                    acc[mf][nf] = __builtin_amdgcn_mfma_f32_16x16x32_bf16(
                        af[mf], bfr[nf], acc[mf][nf], 0, 0, 0);
        }
    }
    #pragma unroll
    for (int mf = 0; mf < 2; ++mf) {
        #pragma unroll
        for (int rr = 0; rr < 4; ++rr) {
            int gm = m0 + wm + mf * 16 + (lane >> 4) * 4 + rr;
            #pragma unroll
            for (int nf = 0; nf < 2; ++nf) {
                int e = n0 + wn + nf * 16 + (lane & 15);
                float v = acc[mf][nf][rr];
                if (p.bias) v += p.bias[e];
                if (p.relu) v = fmaxf(v, 0.f);
                if (p.accs) v += p.accs[(size_t)gm * p.ldo + e];
                size_t oo = (size_t)gm * p.ldo + e + (size_t)z * p.zOutOff;
                if (p.outF) p.outF[oo] = v;
                if (p.outB) p.outB[oo] = f2bf(v);
            }
        }
    }
}

// ---------- p[tok][h][d] = sum_dh kwT[h*64+dh][d]*qs[tok][h*64+dh]; c[tok][h] ----------
__global__ __launch_bounds__(256) void k_prep2(const float* __restrict__ qs, int qld,
                                               const float* __restrict__ kwT,
                                               const float* __restrict__ k_b,
                                               unsigned short* __restrict__ p,
                                               float* __restrict__ c) {
    __shared__ float q8[8][512];
    int t = threadIdx.x;
    int tok0 = blockIdx.x * 8;
    int d = blockIdx.y * 256 + t;
    for (int idx = t; idx < 4096; idx += 256) {
        int s = idx >> 9, dd = idx & 511;
        q8[s][dd] = qs[(size_t)(tok0 + s) * qld + dd];
    }
    __syncthreads();
    if (blockIdx.y == 0 && t < 64) {
        int s = t >> 3, hh = t & 7;
        float cv = 0.f;
        for (int dh = 0; dh < 64; ++dh) cv += k_b[hh * 64 + dh] * q8[s][hh * 64 + dh];
        c[(tok0 + s) * 8 + hh] = cv;
    }
    for (int hh = 0; hh < 8; ++hh) {
        float pv[8];
        #pragma unroll
        for (int s = 0; s < 8; ++s) pv[s] = 0.f;
        for (int dh = 0; dh < 64; ++dh) {
            float wv = kwT[(size_t)(hh * 64 + dh) * 512 + d];
            #pragma unroll
            for (int s = 0; s < 8; ++s) pv[s] += wv * q8[s][hh * 64 + dh];
        }
        #pragma unroll
        for (int s = 0; s < 8; ++s)
            p[((size_t)(tok0 + s) * 8 + hh) * 512 + d] = f2bf(pv[s]);
    }
}

// ---------- edge MLP: U = relu(fixed[tokI] + arc@W2 + row[tokJ]) -> bf16 ----------
// R7 gload_lds structure + LDS double-buffer + COUNTED vmcnt (T3+T4, m201 recipe):
// issue next step's 12 gload_lds per wave, wait vmcnt(12) (only current step's
// loads drained), raw s_barrier, compute, barrier. Loads stay in flight across
// both barriers. Last iteration waits vmcnt(0).
__global__ __launch_bounds__(256) void k_midU(const float* __restrict__ arc,
                                              const unsigned short* __restrict__ W2t,
                                              const float* __restrict__ fixedMat, int fld,
                                              const float* __restrict__ rowMat, int rld,
                                              unsigned short* __restrict__ U) {
    __shared__ float As4[2][128 * 64];            // 2 x 32KB fp32 A
    __shared__ unsigned short Bs2[2][128 * 64];   // 2 x 16KB bf16 B
    int t = threadIdx.x;
    int lane = t & 63;
    int w = t >> 6;
    int bid = blockIdx.x;
    int xcd = bid & 7, slot = bid >> 3;          // round-robin XCD dispatch
    int mt = xcd * 64 + (slot >> 2);             // 0..511 m-tile
    int nt = slot & 3;                           // 4 n-siblings adjacent on one XCD
    int m0 = mt * 128, n0 = nt * 128;
    int wm = (w >> 1) * 64, wn = (w & 1) * 64;
    f32x4 acc[4][4];
    #pragma unroll
    for (int a = 0; a < 4; ++a)
        #pragma unroll
        for (int bq = 0; bq < 4; ++bq) acc[a][bq] = (f32x4){0.f, 0.f, 0.f, 0.f};

    // staging geometry (per wave: 8 A-issues + 4 B-issues = 12)
    int arA = lane >> 4;                 // A: row within 4-row group
    int acb = lane & 15;                 // A: 16B chunk within 256B row
    int brB = lane >> 3;                 // B: row within 8-row group
    int bcb = lane & 7;                  // B: 16B chunk within 128B row

#define ISSUE(KB, BUF)                                                          \
    _Pragma("unroll")                                                           \
    for (int i = 0; i < 8; ++i) {                                               \
        int base = (w * 8 + i) * 1024;                                          \
        int r = ((w * 8 + i) << 2) + arA;                                       \
        int cs = acb ^ (r & 7);                                                 \
        gload16(arc + (size_t)(m0 + r) * 512 + (KB) + cs * 4,                   \
                (char*)As4[BUF] + base);                                        \
    }                                                                           \
    _Pragma("unroll")                                                           \
    for (int i = 0; i < 4; ++i) {                                               \
        int base = (w * 4 + i) * 1024;                                          \
        int r = ((w * 4 + i) << 3) + brB;                                       \
        int cs = bcb ^ (r & 7);                                                 \
        gload16(W2t + (size_t)(n0 + r) * 512 + (KB) + cs * 8,                   \
                (char*)Bs2[BUF] + base);                                        \
    }

    ISSUE(0, 0);
    #pragma unroll
    for (int kb8 = 0; kb8 < 8; ++kb8) {
        int cur = kb8 & 1;
        if (kb8 < 7) {
            ISSUE((kb8 + 1) * 64, cur ^ 1);      // prefetch next step
            asm volatile("s_waitcnt vmcnt(12)" ::: "memory");  // only cur's landed
        } else {
            asm volatile("s_waitcnt vmcnt(0)" ::: "memory");
        }
        __builtin_amdgcn_s_barrier();            // all waves' cur loads visible
        #pragma unroll
        for (int kh = 0; kh < 2; ++kh) {
            int kk = kh * 32 + (lane >> 4) * 8;  // fp32 k-col
            bf16x8 af[4], bfr[4];
            #pragma unroll
            for (int mf = 0; mf < 4; ++mf) {
                int rr = wm + mf * 16 + (lane & 15);
                int c0 = kk >> 2;
                const char* bp = (const char*)As4[cur] + rr * 256;
                float4 a0 = *reinterpret_cast<const float4*>(bp + ((c0 ^ (rr & 7)) << 4));
                float4 a1 = *reinterpret_cast<const float4*>(bp + (((c0 + 1) ^ (rr & 7)) << 4));
                af[mf][0] = (__bf16)a0.x; af[mf][1] = (__bf16)a0.y;
                af[mf][2] = (__bf16)a0.z; af[mf][3] = (__bf16)a0.w;
                af[mf][4] = (__bf16)a1.x; af[mf][5] = (__bf16)a1.y;
                af[mf][6] = (__bf16)a1.z; af[mf][7] = (__bf16)a1.w;
            }
            #pragma unroll
            for (int nf = 0; nf < 4; ++nf) {
                int rn = wn + nf * 16 + (lane & 15);
                int c = kk >> 3;
                bfr[nf] = *reinterpret_cast<const bf16x8*>(
                    (const char*)Bs2[cur] + rn * 128 + ((c ^ (rn & 7)) << 4));
            }
            #pragma unroll
            for (int mf = 0; mf < 4; ++mf)
                #pragma unroll
                for (int nf = 0; nf < 4; ++nf)
                    acc[mf][nf] = __builtin_amdgcn_mfma_f32_16x16x32_bf16(
                        af[mf], bfr[nf], acc[mf][nf], 0, 0, 0);
        }
        if (kb8 < 7) __builtin_amdgcn_s_barrier();   // protect cur before reuse
    }
#undef ISSUE
    int tokI = mt;
    int bb = mt >> 7;
    float fx[4];
    #pragma unroll
    for (int nf = 0; nf < 4; ++nf)
        fx[nf] = fixedMat[(size_t)tokI * fld + n0 + wn + nf * 16 + (lane & 15)];
    #pragma unroll
    for (int mf = 0; mf < 4; ++mf) {
        #pragma unroll
        for (int r = 0; r < 4; ++r) {
            int row = wm + mf * 16 + (lane >> 4) * 4 + r;
            int gm = m0 + row;
            int tokJ = bb * 128 + (gm & 127);
            const float* rv = rowMat + (size_t)tokJ * rld;
            #pragma unroll
            for (int nf = 0; nf < 4; ++nf) {
                int e = n0 + wn + nf * 16 + (lane & 15);
                float v = acc[mf][nf][r] + fx[nf] + rv[e];
                v = fmaxf(v, 0.f);
                U[(size_t)gm * 512 + e] = f2bf(v);
            }
        }
    }
}

// ---------- scores + softmax: attn[tok][h][j]; 4 waves per tok (32 j each) ----------
__global__ __launch_bounds__(256) void k_scores(const unsigned short* __restrict__ U,
                                                const unsigned short* __restrict__ p,
                                                const float* __restrict__ c,
                                                float* __restrict__ attn) {
    __shared__ float sc[8][128];
    int tok = blockIdx.x;
    int t = threadIdx.x;
    int w = t >> 6;
    int lane = t & 63;
    int hh = lane & 15;
    int kg = lane >> 4;
    bool hv = hh < 8;
    f32x4 acc[2];
    acc[0] = (f32x4){0.f, 0.f, 0.f, 0.f};
    acc[1] = (f32x4){0.f, 0.f, 0.f, 0.f};
    const unsigned short* Ub = U + (size_t)tok * 65536 + (size_t)(w * 32) * 512;
    const unsigned short* pb = p + ((size_t)tok * 8 + (hh & 7)) * 512;
    for (int ks = 0; ks < 16; ++ks) {
        int kcol = ks * 32 + kg * 8;
        u32x4 braw = (u32x4){0u, 0u, 0u, 0u};
        if (hv) braw = *reinterpret_cast<const u32x4*>(pb + kcol);
        bf16x8 bfrag = __builtin_bit_cast(bf16x8, braw);
        #pragma unroll
        for (int mf = 0; mf < 2; ++mf) {
            bf16x8 afrag = *reinterpret_cast<const bf16x8*>(
                Ub + (size_t)(mf * 16 + hh) * 512 + kcol);
            acc[mf] = __builtin_amdgcn_mfma_f32_16x16x32_bf16(afrag, bfrag, acc[mf], 0, 0, 0);
        }
    }
    if (hv) {
        float cval = c[tok * 8 + hh];
        #pragma unroll
        for (int mf = 0; mf < 2; ++mf)
            #pragma unroll
            for (int r = 0; r < 4; ++r)
                sc[hh][w * 32 + mf * 16 + kg * 4 + r] = acc[mf][r] + cval;
    }
    __syncthreads();
    int h2 = t >> 5, l32 = t & 31;               // 8 h-groups x 32 lanes
    float v0 = sc[h2][l32], v1 = sc[h2][l32 + 32],
          v2 = sc[h2][l32 + 64], v3 = sc[h2][l32 + 96];
    float mx = fmaxf(fmaxf(v0, v1), fmaxf(v2, v3));
    #pragma unroll
    for (int o = 16; o >= 1; o >>= 1) mx = fmaxf(mx, __shfl_xor(mx, o));
    float e0 = __expf(v0 - mx), e1 = __expf(v1 - mx),
          e2 = __expf(v2 - mx), e3 = __expf(v3 - mx);
    float sum = e0 + e1 + e2 + e3;
    #pragma unroll
    for (int o = 16; o >= 1; o >>= 1) sum += __shfl_xor(sum, o);
    float inv = 1.f / sum;
    float* ab = attn + (size_t)tok * 1024 + h2 * 128;
    ab[l32]      = e0 * inv;
    ab[l32 + 32] = e1 * inv;
    ab[l32 + 64] = e2 * inv;
    ab[l32 + 96] = e3 * inv;
}

// ---------- Wacc[tok][h][d] = sum_j attn[tok][h][j]*U[tok][j][d] -> bf16 ----------
__global__ __launch_bounds__(256) void k_wacc(const unsigned short* __restrict__ U,
                                              const float* __restrict__ attn,
                                              unsigned short* __restrict__ Wacc) {
    __shared__ float at[1024];
    int t = threadIdx.x;
    int tok = blockIdx.x;
    for (int idx = t; idx < 1024; idx += 256) at[idx] = attn[(size_t)tok * 1024 + idx];
    __syncthreads();
    int d0 = t * 2;
    const unsigned short* Ub = U + (size_t)tok * 65536;
    float acc[8][2];
    #pragma unroll
    for (int hh = 0; hh < 8; ++hh) { acc[hh][0] = 0.f; acc[hh][1] = 0.f; }
    for (int j = 0; j < 128; ++j) {
        unsigned int uv = *reinterpret_cast<const unsigned int*>(Ub + (size_t)j * 512 + d0);
        float u0 = bf2f((unsigned short)(uv & 0xffffu));
        float u1 = bf2f((unsigned short)(uv >> 16));
        #pragma unroll
        for (int hh = 0; hh < 8; ++hh) {
            float a = at[hh * 128 + j];
            acc[hh][0] += a * u0;
            acc[hh][1] += a * u1;
        }
    }
    #pragma unroll
    for (int hh = 0; hh < 8; ++hh) {
        unsigned short* wp = Wacc + ((size_t)tok * 8 + hh) * 512 + d0;
        wp[0] = f2bf(acc[hh][0]);
        wp[1] = f2bf(acc[hh][1]);
    }
}

// ---------- layernorm: out = LN(A + B) * g + beta ----------
__global__ __launch_bounds__(256) void k_ln(const float* __restrict__ A,
                                            const float* __restrict__ Bv, int bswap,
                                            const float* __restrict__ parts,
                                            const float* __restrict__ pbias,
                                            const float* __restrict__ g,
                                            const float* __restrict__ bta,
                                            float* __restrict__ outF,
                                            unsigned short* __restrict__ outB) {
    int t = threadIdx.x;
    int tok = blockIdx.x;
    size_t aoff = (size_t)tok * 512;
    float b0, b1;
    if (parts) {
        b0 = parts[aoff + t] + parts[262144 + aoff + t] +
             parts[524288 + aoff + t] + parts[786432 + aoff + t] + pbias[t];
        b1 = parts[aoff + t + 256] + parts[262144 + aoff + t + 256] +
             parts[524288 + aoff + t + 256] + parts[786432 + aoff + t + 256] + pbias[t + 256];
    } else {
        size_t boff = aoff;
        if (bswap) { int i = tok >> 2, b = tok & 3; boff = (size_t)(b * 128 + i) * 512; }
        b0 = Bv[boff + t];
        b1 = Bv[boff + t + 256];
    }
    float v0 = A[aoff + t] + b0;
    float v1 = A[aoff + t + 256] + b1;
    float s = v0 + v1, q = v0 * v0 + v1 * v1;
    #pragma unroll
    for (int o = 32; o >= 1; o >>= 1) { s += __shfl_xor(s, o); q += __shfl_xor(q, o); }
    __shared__ float red[8];
    int w = t >> 6, lane = t & 63;
    if (lane == 0) { red[w] = s; red[4 + w] = q; }
    __syncthreads();
    float ts = red[0] + red[1] + red[2] + red[3];
    float tq = red[4] + red[5] + red[6] + red[7];
    float mean = ts * (1.f / 512.f);
    float var = tq * (1.f / 512.f) - mean * mean;
    float inv = rsqrtf(var + 1e-5f);
    float o0 = (v0 - mean) * inv * g[t] + bta[t];
    float o1 = (v1 - mean) * inv * g[t + 256] + bta[t + 256];
    outF[aoff + t] = o0;
    outF[aoff + t + 256] = o1;
    if (outB) { outB[aoff + t] = f2bf(o0); outB[aoff + t + 256] = f2bf(o1); }
}

extern "C" void kernel_launch(void* const* d_in, const int* in_sizes, int n_in,
                              void* d_out, int out_size, void* d_ws, size_t ws_size,
                              hipStream_t stream) {
    (void)in_sizes; (void)n_in; (void)out_size; (void)ws_size;
    const float* h       = (const float*)d_in[0];
    const float* arc_out = (const float*)d_in[1];
    const float* arc_in  = (const float*)d_in[2];
    const float* W_out_w = (const float*)d_in[4];
    const float* W_out_b = (const float*)d_in[5];
    const float* W_in_w  = (const float*)d_in[6];
    const float* W_in_b  = (const float*)d_in[7];
    const float* q_w  = (const float*)d_in[8];
    const float* q_b  = (const float*)d_in[9];
    const float* k_w  = (const float*)d_in[10];
    const float* k_b  = (const float*)d_in[11];
    const float* v_w  = (const float*)d_in[12];
    const float* v_b  = (const float*)d_in[13];
    const float* o_w  = (const float*)d_in[14];
    const float* o_b  = (const float*)d_in[15];
    const float* ln1_g = (const float*)d_in[16];
    const float* ln1_b = (const float*)d_in[17];
    const float* fc1_w = (const float*)d_in[18];
    const float* fc1_b = (const float*)d_in[19];
    const float* fc2_w = (const float*)d_in[20];
    const float* fc2_b = (const float*)d_in[21];
    const float* ln2_g = (const float*)d_in[22];
    const float* ln2_b = (const float*)d_in[23];
    float* out = (float*)d_out;

    char* wsb = (char*)d_ws;
    size_t off = 0;
    auto ALLOC = [&](size_t bytes) -> void* {
        void* ptr = wsb + off;
        off += (bytes + 255) & ~(size_t)255;
        return ptr;
    };
    unsigned short* WcatT = (unsigned short*)ALLOC((size_t)2560 * 512 * 2);
    unsigned short* W2to  = (unsigned short*)ALLOC(262144 * 2);
    unsigned short* W2ti  = (unsigned short*)ALLOC(262144 * 2);
    unsigned short* o_wT  = (unsigned short*)ALLOC(262144 * 2);
    unsigned short* v_wT  = (unsigned short*)ALLOC(262144 * 2);
    unsigned short* fc1T  = (unsigned short*)ALLOC((size_t)2048 * 512 * 2);
    unsigned short* fc2T  = (unsigned short*)ALLOC((size_t)512 * 2048 * 2);
    float* kwT   = (float*)ALLOC(262144 * 4);
    float* bias1 = (float*)ALLOC(2560 * 4);
    unsigned short* Qm = (unsigned short*)ALLOC(262144 * 2);
    float* QWcat = (float*)ALLOC((size_t)512 * 2560 * 4);
    unsigned short* pbuf = (unsigned short*)ALLOC((size_t)NTOK * 8 * 512 * 2);
    float* cbuf = (float*)ALLOC(NTOK * 8 * 4);
    unsigned short* Ubuf = (unsigned short*)ALLOC((size_t)NM * 512 * 2);
    float* attnb = (float*)ALLOC((size_t)NTOK * 8 * 128 * 4);
    unsigned short* Waccb = (unsigned short*)ALLOC((size_t)NTOK * 8 * 512 * 2);
    unsigned short* tmpb  = (unsigned short*)ALLOC(262144 * 2);
    float* attsum = (float*)ALLOC(262144 * 4);
    float* x1  = (float*)ALLOC(262144 * 4);
    unsigned short* x1b = (unsigned short*)ALLOC(262144 * 2);
    unsigned short* ybb = (unsigned short*)ALLOC((size_t)NTOK * 2048 * 2);
    float* zparts = (float*)ALLOC((size_t)4 * 262144 * 4);

    k_qtrans<<<1024, 256, 0, stream>>>(h, Qm);

    // merged weight transposes (fp32 -> bf16 N x K)
    {
        TRJobs js = {};
        auto SET = [&](int i, const float* s, int sld, unsigned short* d, int dld,
                       float sc, int tiles, int tcols) {
            js.j[i] = TRJob{s, d, sld, dld, tcols, sc};
            js.start[i + 1] = js.start[i] + tiles;
        };
        js.start[0] = 0;
        SET(0,  W_out_w,              512, WcatT,              512, 1.f,    64, 8);
        SET(1,  W_out_w + 1024 * 512, 512, WcatT + 512 * 512,  512, 1.f,    64, 8);
        SET(2,  W_in_w,               512, WcatT + 1024 * 512, 512, 1.f,    64, 8);
        SET(3,  W_in_w + 1024 * 512,  512, WcatT + 1536 * 512, 512, 1.f,    64, 8);
        SET(4,  q_w,                  512, WcatT + 2048 * 512, 512, 0.125f, 64, 8);
        SET(5,  W_out_w + 512 * 512,  512, W2to,               512, 1.f,    64, 8);
        SET(6,  W_in_w + 512 * 512,   512, W2ti,               512, 1.f,    64, 8);
        SET(7,  o_w,                  512, o_wT,               512, 1.f,    64, 8);
        SET(8,  v_w,                  512, v_wT,               512, 1.f,    64, 8);
        SET(9,  fc1_w,               2048, fc1T,               512, 1.f,   256, 32);
        SET(10, fc2_w,                512, fc2T,              2048, 1.f,   256, 8);
        k_trN<<<js.start[11], 256, 0, stream>>>(js);
    }
    k_kwT<<<1024, 256, 0, stream>>>(k_w, kwT);
    k_bias1<<<10, 256, 0, stream>>>(W_out_b, W_in_b, q_b, bias1);

    // batched Q-side projections: QWcat = Qm @ [W1o|W3o|W1i|W3i|q*.125] + bias1
    {
        MMP m = {};
        m.A = Qm; m.lda = 512; m.Bt = WcatT; m.ldb = 512;
        m.bias = bias1; m.outF = QWcat; m.ldo = 2560; m.K = 512;
        k_mm<<<dim3(8, 40), 256, 0, stream>>>(m);
    }
    k_prep2<<<dim3(64, 2), 256, 0, stream>>>(QWcat + 2048, 2560, kwT, k_b, pbuf, cbuf);

    for (int arc = 0; arc < 2; ++arc) {
        const float* arcp = (arc == 0) ? arc_out : arc_in;
        const unsigned short* w2 = (arc == 0) ? W2to : W2ti;
        const float* fixedM = (arc == 0) ? QWcat + 0    : QWcat + 1536;  // QW1o : QW3i
        const float* rowM   = (arc == 0) ? QWcat + 512  : QWcat + 1024;  // QW3o : QW1i
        k_midU<<<2048, 256, 0, stream>>>(arcp, w2, fixedM, 2560, rowM, 2560, Ubuf);
        k_scores<<<512, 256, 0, stream>>>(Ubuf, pbuf, cbuf, attnb);
        k_wacc<<<512, 256, 0, stream>>>(Ubuf, attnb, Waccb);
        {
            MMP m = {};
            m.A = Waccb; m.lda = 4096; m.aOffPerN64 = 512;
            m.Bt = v_wT; m.ldb = 512;
            m.bias = v_b; m.outB = tmpb; m.ldo = 512; m.K = 512;
            k_mm<<<dim3(8, 8), 256, 0, stream>>>(m);
        }
        {
            MMP m = {};
            m.A = tmpb; m.lda = 512; m.Bt = o_wT; m.ldb = 512;
            m.bias = o_b; m.outF = attsum; m.ldo = 512; m.K = 512;
            m.accs = (arc == 0) ? nullptr : attsum;
            k_mm<<<dim3(8, 8), 256, 0, stream>>>(m);
        }
    }

    k_ln<<<512, 256, 0, stream>>>(h, attsum, 1, nullptr, nullptr, ln1_g, ln1_b, x1, x1b);

    {
        MMP m = {};
        m.A = x1b; m.lda = 512; m.Bt = fc1T; m.ldb = 512;
        m.bias = fc1_b; m.relu = 1; m.outB = ybb; m.ldo = 2048; m.K = 512;
        k_mm<<<dim3(8, 32), 256, 0, stream>>>(m);
    }
    {
        MMP m = {};
        m.A = ybb; m.lda = 2048; m.Bt = fc2T; m.ldb = 2048;
        m.outF = zparts; m.ldo = 512; m.K = 512;
        m.zKOff = 512; m.zOutOff = 262144;
        k_mm<<<dim3(8, 8, 4), 256, 0, stream>>>(m);
    }
    k_ln<<<512, 256, 0, stream>>>(x1, nullptr, 0, zparts, fc2_b, ln2_g, ln2_b, out, nullptr);
}

// Round 10
// 342.272 us; speedup vs baseline: 1.3055x; 1.3055x over previous
//
#include <hip/hip_runtime.h>
#include <stdint.h>
#include <stddef.h>

// Shapes: D=512, F=2048, H=8, L=128, B=4
#define NTOK 512      // B*L tokens
#define NM   65536    // B*L*L edge rows

typedef __bf16 bf16x8 __attribute__((ext_vector_type(8)));
typedef float  f32x4  __attribute__((ext_vector_type(4)));
typedef unsigned int u32x4 __attribute__((ext_vector_type(4)));

__device__ __forceinline__ unsigned short f2bf(float f) {
    unsigned int u = __builtin_bit_cast(unsigned int, f);
    u += 0x7FFFu + ((u >> 16) & 1u);
    return (unsigned short)(u >> 16);
}
__device__ __forceinline__ float bf2f(unsigned short s) {
    unsigned int u = ((unsigned int)s) << 16;
    return __builtin_bit_cast(float, u);
}

// async global->LDS, 16B per lane; LDS dest is wave-uniform base + lane*16
__device__ __forceinline__ void gload16(const void* g, void* l) {
    __builtin_amdgcn_global_load_lds(
        (const __attribute__((address_space(1))) void*)g,
        (__attribute__((address_space(3))) void*)l,
        16, 0, 0);
}

// ---------- merged prep: h-transpose + k_w transpose + concat bias ----------
__global__ __launch_bounds__(256) void k_prep(const float* __restrict__ h,
                                              unsigned short* __restrict__ Qm,
                                              const float* __restrict__ kw,
                                              float* __restrict__ kwT,
                                              const float* __restrict__ Wob,
                                              const float* __restrict__ Wib,
                                              const float* __restrict__ qb,
                                              float* __restrict__ bias1) {
    int bid = blockIdx.x;
    int t = threadIdx.x;
    if (bid < 1024) {                       // h (L,B,D) -> Qm bf16 (b*128+i, 512)
        int idx = bid * 256 + t;
        int tok = idx >> 9, d = idx & 511;
        int b = tok >> 7, i = tok & 127;
        Qm[idx] = f2bf(h[(i * 4 + b) * 512 + d]);
    } else if (bid < 2048) {                // kwT[e][d] = k_w[d][e]
        int idx = (bid - 1024) * 256 + t;
        kwT[idx] = kw[(size_t)(idx & 511) * 512 + (idx >> 9)];
    } else {                                // bias1 concat
        int i = (bid - 2048) * 256 + t;
        if (i < 2560) {
            float v = 0.f;
            if (i < 512) v = Wob[i];
            else if (i < 1024) v = 0.f;
            else if (i < 1536) v = Wib[i - 1024];
            else if (i < 2048) v = 0.f;
            else v = qb[i - 2048] * 0.125f;
            bias1[i] = v;
        }
    }
}

// ---------- merged LDS-tiled fp32 -> bf16 transposes (job table) ----------
struct TRJob { const float* src; unsigned short* dst; int srcLd, dstLd, tcols; float scale; };
struct TRJobs { TRJob j[11]; int start[12]; };

__global__ __launch_bounds__(256) void k_trN(TRJobs js) {
    __shared__ float tile[64][65];
    int b = blockIdx.x;
    int ji = 0;
    while (ji < 10 && b >= js.start[ji + 1]) ++ji;
    TRJob jb = js.j[ji];
    int rel = b - js.start[ji];
    int bx = rel % jb.tcols, by = rel / jb.tcols;
    int r0 = by * 64, c0 = bx * 64;
    int t = threadIdx.x;
    int c = t & 63, rr = t >> 6;                // rr in 0..3
    #pragma unroll
    for (int ii = 0; ii < 16; ++ii) {
        int r = ii * 4 + rr;
        tile[r][c] = jb.src[(size_t)(r0 + r) * jb.srcLd + c0 + c];
    }
    __syncthreads();
    #pragma unroll
    for (int ii = 0; ii < 16; ++ii) {
        int n = ii * 4 + rr;                    // local col of src = row of dst
        jb.dst[(size_t)(c0 + n) * jb.dstLd + r0 + c] = f2bf(tile[c][n] * jb.scale);
    }
}

// ---------- generic bf16 MFMA GEMM: out = relu(A@B^T + bias*biasScale) [+accs] ----------
struct MMP {
    const unsigned short* A;  int lda;
    const unsigned short* Bt; int ldb;
    const float* bias;
    const float* accs;
    float* outF;
    unsigned short* outB;
    int ldo;
    int K;
    int relu;
    int aOffPerN64;
    int zKOff;
    int zOutOff;
    float biasScale;
};

__global__ __launch_bounds__(256) void k_mm(MMP p) {
    __shared__ unsigned char As[64 * 128];
    __shared__ unsigned char Bs[64 * 128];
    int t = threadIdx.x;
    int lane = t & 63, w = t >> 6;
    int m0 = blockIdx.x * 64, n0 = blockIdx.y * 64;
    int z = blockIdx.z;
    const unsigned short* A  = p.A + (size_t)(n0 >> 6) * p.aOffPerN64 + (size_t)z * p.zKOff;
    const unsigned short* Bt = p.Bt + (size_t)z * p.zKOff;
    int wm = (w >> 1) * 32, wn = (w & 1) * 32;
    f32x4 acc[2][2];
    #pragma unroll
    for (int a = 0; a < 2; ++a)
        #pragma unroll
        for (int b = 0; b < 2; ++b) acc[a][b] = (f32x4){0.f, 0.f, 0.f, 0.f};

    for (int kb = 0; kb < p.K; kb += 64) {
        __syncthreads();
        #pragma unroll
        for (int s = 0; s < 2; ++s) {
            int c = t + s * 256;
            int r = c >> 3, kc = (c & 7) * 8;
            int off = (r * 128 + kc * 2) ^ ((r & 7) << 4);
            *reinterpret_cast<u32x4*>(As + off) =
                *reinterpret_cast<const u32x4*>(A + (size_t)(m0 + r) * p.lda + kb + kc);
            *reinterpret_cast<u32x4*>(Bs + off) =
                *reinterpret_cast<const u32x4*>(Bt + (size_t)(n0 + r) * p.ldb + kb + kc);
        }
        __syncthreads();
        #pragma unroll
        for (int kh = 0; kh < 2; ++kh) {
            int kk = kh * 32 + (lane >> 4) * 8;
            bf16x8 af[2], bfr[2];
            #pragma unroll
            for (int mf = 0; mf < 2; ++mf) {
                int r = wm + mf * 16 + (lane & 15);
                int off = (r * 128 + kk * 2) ^ ((r & 7) << 4);
                af[mf] = *reinterpret_cast<const bf16x8*>(As + off);
            }
            #pragma unroll
            for (int nf = 0; nf < 2; ++nf) {
                int r = wn + nf * 16 + (lane & 15);
                int off = (r * 128 + kk * 2) ^ ((r & 7) << 4);
                bfr[nf] = *reinterpret_cast<const bf16x8*>(Bs + off);
            }
            #pragma unroll
            for (int mf = 0; mf < 2; ++mf)
                #pragma unroll
                for (int nf = 0; nf < 2; ++nf)
                    acc[mf][nf] = __builtin_amdgcn_mfma_f32_16x16x32_bf16(
                        af[mf], bfr[nf], acc[mf][nf], 0, 0, 0);
        }
    }
    #pragma unroll
    for (int mf = 0; mf < 2; ++mf) {
        #pragma unroll
        for (int rr = 0; rr < 4; ++rr) {
            int gm = m0 + wm + mf * 16 + (lane >> 4) * 4 + rr;
            #pragma unroll
            for (int nf = 0; nf < 2; ++nf) {
                int e = n0 + wn + nf * 16 + (lane & 15);
                float v = acc[mf][nf][rr];
                if (p.bias) v += p.bias[e] * p.biasScale;
                if (p.relu) v = fmaxf(v, 0.f);
                if (p.accs) v += p.accs[(size_t)gm * p.ldo + e];
                size_t oo = (size_t)gm * p.ldo + e + (size_t)z * p.zOutOff;
                if (p.outF) p.outF[oo] = v;
                if (p.outB) p.outB[oo] = f2bf(v);
            }
        }
    }
}

// ---------- p[tok][h][d] = sum_dh kwT[h*64+dh][d]*qs[tok][h*64+dh]; c[tok][h] ----------
__global__ __launch_bounds__(256) void k_prep2(const float* __restrict__ qs, int qld,
                                               const float* __restrict__ kwT,
                                               const float* __restrict__ k_b,
                                               unsigned short* __restrict__ p,
                                               float* __restrict__ c) {
    __shared__ float q8[8][512];
    int t = threadIdx.x;
    int tok0 = blockIdx.x * 8;
    int d = blockIdx.y * 256 + t;
    for (int idx = t; idx < 4096; idx += 256) {
        int s = idx >> 9, dd = idx & 511;
        q8[s][dd] = qs[(size_t)(tok0 + s) * qld + dd];
    }
    __syncthreads();
    if (blockIdx.y == 0 && t < 64) {
        int s = t >> 3, hh = t & 7;
        float cv = 0.f;
        for (int dh = 0; dh < 64; ++dh) cv += k_b[hh * 64 + dh] * q8[s][hh * 64 + dh];
        c[(tok0 + s) * 8 + hh] = cv;
    }
    for (int hh = 0; hh < 8; ++hh) {
        float pv[8];
        #pragma unroll
        for (int s = 0; s < 8; ++s) pv[s] = 0.f;
        for (int dh = 0; dh < 64; ++dh) {
            float wv = kwT[(size_t)(hh * 64 + dh) * 512 + d];
            #pragma unroll
            for (int s = 0; s < 8; ++s) pv[s] += wv * q8[s][hh * 64 + dh];
        }
        #pragma unroll
        for (int s = 0; s < 8; ++s)
            p[((size_t)(tok0 + s) * 8 + hh) * 512 + d] = f2bf(pv[s]);
    }
}

// ---------- edge MLP: U = relu(fixed[tokI] + arc@W2 + row[tokJ]) -> bf16 ----------
// R7 structure (best measured): gload_lds staging, A raw fp32 (no VGPR trip),
// converted to bf16 at fragment-read; B bf16. LDS linear dest for gload,
// swizzle on per-lane GLOBAL source + on LDS reads (rule #21). 48KB, 1 buffer.
__global__ __launch_bounds__(256) void k_midU(const float* __restrict__ arc,
                                              const unsigned short* __restrict__ W2t,
                                              const float* __restrict__ fixedMat, int fld,
                                              const float* __restrict__ rowMat, int rld,
                                              unsigned short* __restrict__ U) {
    __shared__ float As4[128 * 64];            // 32KB fp32 A tile (swizzled storage)
    __shared__ unsigned short Bs2[128 * 64];   // 16KB bf16 B tile
    int t = threadIdx.x;
    int lane = t & 63;
    int w = t >> 6;
    int bid = blockIdx.x;
    int xcd = bid & 7, slot = bid >> 3;          // round-robin XCD dispatch
    int mt = xcd * 64 + (slot >> 2);             // 0..511 m-tile
    int nt = slot & 3;                           // 4 n-siblings adjacent on one XCD
    int m0 = mt * 128;
    int n0 = nt * 128;
    int wm = (w >> 1) * 64, wn = (w & 1) * 64;
    f32x4 acc[4][4];
    #pragma unroll
    for (int a = 0; a < 4; ++a)
        #pragma unroll
        for (int bq = 0; bq < 4; ++bq) acc[a][bq] = (f32x4){0.f, 0.f, 0.f, 0.f};

    // per-lane staging geometry (constant across K-steps)
    int arA = lane >> 4;                 // A: row within 4-row group
    int acb = lane & 15;                 // A: 16B chunk within 256B row
    int brB = lane >> 3;                 // B: row within 8-row group
    int bcb = lane & 7;                  // B: 16B chunk within 128B row

    for (int kb8 = 0; kb8 < 8; ++kb8) {
        int kb = kb8 * 64;
        __syncthreads();                 // prior compute done before overwrite
        #pragma unroll
        for (int i = 0; i < 8; ++i) {
            int base = (w * 8 + i) * 1024;           // wave-uniform LDS byte base
            int r = ((w * 8 + i) << 2) + arA;        // global row in tile
            int cs = acb ^ (r & 7);                  // pre-swizzled source chunk
            gload16(arc + (size_t)(m0 + r) * 512 + kb + cs * 4,
                    (char*)As4 + base);
        }
        #pragma unroll
        for (int i = 0; i < 4; ++i) {
            int base = (w * 4 + i) * 1024;
            int r = ((w * 4 + i) << 3) + brB;
            int cs = bcb ^ (r & 7);
            gload16(W2t + (size_t)(n0 + r) * 512 + kb + cs * 8,
                    (char*)Bs2 + base);
        }
        __syncthreads();                 // vmcnt drained -> tiles ready
        #pragma unroll
        for (int kh = 0; kh < 2; ++kh) {
            int kk = kh * 32 + (lane >> 4) * 8;      // fp32 k-col
            bf16x8 af[4], bfr[4];
            #pragma unroll
            for (int mf = 0; mf < 4; ++mf) {
                int rr = wm + mf * 16 + (lane & 15);
                int c0 = kk >> 2;
                const char* bp = (const char*)As4 + rr * 256;
                float4 a0 = *reinterpret_cast<const float4*>(bp + ((c0 ^ (rr & 7)) << 4));
                float4 a1 = *reinterpret_cast<const float4*>(bp + (((c0 + 1) ^ (rr & 7)) << 4));
                af[mf][0] = (__bf16)a0.x; af[mf][1] = (__bf16)a0.y;
                af[mf][2] = (__bf16)a0.z; af[mf][3] = (__bf16)a0.w;
                af[mf][4] = (__bf16)a1.x; af[mf][5] = (__bf16)a1.y;
                af[mf][6] = (__bf16)a1.z; af[mf][7] = (__bf16)a1.w;
            }
            #pragma unroll
            for (int nf = 0; nf < 4; ++nf) {
                int rn = wn + nf * 16 + (lane & 15);
                int c = kk >> 3;
                bfr[nf] = *reinterpret_cast<const bf16x8*>(
                    (const char*)Bs2 + rn * 128 + ((c ^ (rn & 7)) << 4));
            }
            #pragma unroll
            for (int mf = 0; mf < 4; ++mf)
                #pragma unroll
                for (int nf = 0; nf < 4; ++nf)
                    acc[mf][nf] = __builtin_amdgcn_mfma_f32_16x16x32_bf16(
                        af[mf], bfr[nf], acc[mf][nf], 0, 0, 0);
        }
    }
    int tokI = mt;
    int bb = mt >> 7;
    float fx[4];
    #pragma unroll
    for (int nf = 0; nf < 4; ++nf)
        fx[nf] = fixedMat[(size_t)tokI * fld + n0 + wn + nf * 16 + (lane & 15)];
    #pragma unroll
    for (int mf = 0; mf < 4; ++mf) {
        #pragma unroll
        for (int r = 0; r < 4; ++r) {
            int row = wm + mf * 16 + (lane >> 4) * 4 + r;
            int gm = m0 + row;
            int tokJ = bb * 128 + (gm & 127);
            const float* rv = rowMat + (size_t)tokJ * rld;
            #pragma unroll
            for (int nf = 0; nf < 4; ++nf) {
                int e = n0 + wn + nf * 16 + (lane & 15);
                float v = acc[mf][nf][r] + fx[nf] + rv[e];
                v = fmaxf(v, 0.f);
                U[(size_t)gm * 512 + e] = f2bf(v);
            }
        }
    }
}

// ---------- fused scores+softmax+wacc (attn kept in 4KB LDS) ----------
// accum=0: Wsum (fp32) = attn@U ; accum=1: Waccb (bf16) = Wsum + attn@U
__global__ __launch_bounds__(256) void k_att2(const unsigned short* __restrict__ U,
                                              const unsigned short* __restrict__ p,
                                              const float* __restrict__ c,
                                              float* __restrict__ Wsum,
                                              unsigned short* __restrict__ Waccb,
                                              int accum) {
    __shared__ float at[8][128];
    int tok = blockIdx.x;
    int t = threadIdx.x;
    int w = t >> 6;
    int lane = t & 63;
    int hh = lane & 15;
    int kg = lane >> 4;
    bool hv = hh < 8;
    f32x4 acc[2];
    acc[0] = (f32x4){0.f, 0.f, 0.f, 0.f};
    acc[1] = (f32x4){0.f, 0.f, 0.f, 0.f};
    const unsigned short* Ub0 = U + (size_t)tok * 65536;
    const unsigned short* Ub = Ub0 + (size_t)(w * 32) * 512;
    const unsigned short* pb = p + ((size_t)tok * 8 + (hh & 7)) * 512;
    for (int ks = 0; ks < 16; ++ks) {
        int kcol = ks * 32 + kg * 8;
        u32x4 braw = (u32x4){0u, 0u, 0u, 0u};
        if (hv) braw = *reinterpret_cast<const u32x4*>(pb + kcol);
        bf16x8 bfrag = __builtin_bit_cast(bf16x8, braw);
        #pragma unroll
        for (int mf = 0; mf < 2; ++mf) {
            bf16x8 afrag = *reinterpret_cast<const bf16x8*>(
                Ub + (size_t)(mf * 16 + hh) * 512 + kcol);
            acc[mf] = __builtin_amdgcn_mfma_f32_16x16x32_bf16(afrag, bfrag, acc[mf], 0, 0, 0);
        }
    }
    if (hv) {
        float cval = c[tok * 8 + hh];
        #pragma unroll
        for (int mf = 0; mf < 2; ++mf)
            #pragma unroll
            for (int r = 0; r < 4; ++r)
                at[hh][w * 32 + mf * 16 + kg * 4 + r] = acc[mf][r] + cval;
    }
    __syncthreads();
    // softmax in place over j per head (8 groups x 32 lanes)
    {
        int h2 = t >> 5, l32 = t & 31;
        float v0 = at[h2][l32], v1 = at[h2][l32 + 32],
              v2 = at[h2][l32 + 64], v3 = at[h2][l32 + 96];
        float mx = fmaxf(fmaxf(v0, v1), fmaxf(v2, v3));
        #pragma unroll
        for (int o = 16; o >= 1; o >>= 1) mx = fmaxf(mx, __shfl_xor(mx, o));
        float e0 = __expf(v0 - mx), e1 = __expf(v1 - mx),
              e2 = __expf(v2 - mx), e3 = __expf(v3 - mx);
        float sum = e0 + e1 + e2 + e3;
        #pragma unroll
        for (int o = 16; o >= 1; o >>= 1) sum += __shfl_xor(sum, o);
        float inv = 1.f / sum;
        at[h2][l32]      = e0 * inv;
        at[h2][l32 + 32] = e1 * inv;
        at[h2][l32 + 64] = e2 * inv;
        at[h2][l32 + 96] = e3 * inv;
    }
    __syncthreads();
    // wacc: thread t covers d0=2t, all 8 heads; U re-read (L2/L3-hot)
    int d0 = t * 2;
    float a8[8][2];
    #pragma unroll
    for (int q = 0; q < 8; ++q) { a8[q][0] = 0.f; a8[q][1] = 0.f; }
    for (int j = 0; j < 128; ++j) {
        unsigned int uv = *reinterpret_cast<const unsigned int*>(Ub0 + (size_t)j * 512 + d0);
        float u0 = bf2f((unsigned short)(uv & 0xffffu));
        float u1 = bf2f((unsigned short)(uv >> 16));
        #pragma unroll
        for (int q = 0; q < 8; ++q) {
            float a = at[q][j];
            a8[q][0] += a * u0;
            a8[q][1] += a * u1;
        }
    }
    #pragma unroll
    for (int q = 0; q < 8; ++q) {
        size_t woff = ((size_t)tok * 8 + q) * 512 + d0;
        if (!accum) {
            Wsum[woff] = a8[q][0];
            Wsum[woff + 1] = a8[q][1];
        } else {
            float s0 = Wsum[woff] + a8[q][0];
            float s1 = Wsum[woff + 1] + a8[q][1];
            Waccb[woff] = f2bf(s0);
            Waccb[woff + 1] = f2bf(s1);
        }
    }
}

// ---------- layernorm: out = LN(A + B) * g + beta ----------
__global__ __launch_bounds__(256) void k_ln(const float* __restrict__ A,
                                            const float* __restrict__ Bv, int bswap,
                                            const float* __restrict__ parts,
                                            const float* __restrict__ pbias,
                                            const float* __restrict__ g,
                                            const float* __restrict__ bta,
                                            float* __restrict__ outF,
                                            unsigned short* __restrict__ outB) {
    int t = threadIdx.x;
    int tok = blockIdx.x;
    size_t aoff = (size_t)tok * 512;
    float b0, b1;
    if (parts) {
        b0 = parts[aoff + t] + parts[262144 + aoff + t] +
             parts[524288 + aoff + t] + parts[786432 + aoff + t] + pbias[t];
        b1 = parts[aoff + t + 256] + parts[262144 + aoff + t + 256] +
             parts[524288 + aoff + t + 256] + parts[786432 + aoff + t + 256] + pbias[t + 256];
    } else {
        size_t boff = aoff;
        if (bswap) { int i = tok >> 2, b = tok & 3; boff = (size_t)(b * 128 + i) * 512; }
        b0 = Bv[boff + t];
        b1 = Bv[boff + t + 256];
    }
    float v0 = A[aoff + t] + b0;
    float v1 = A[aoff + t + 256] + b1;
    float s = v0 + v1, q = v0 * v0 + v1 * v1;
    #pragma unroll
    for (int o = 32; o >= 1; o >>= 1) { s += __shfl_xor(s, o); q += __shfl_xor(q, o); }
    __shared__ float red[8];
    int w = t >> 6, lane = t & 63;
    if (lane == 0) { red[w] = s; red[4 + w] = q; }
    __syncthreads();
    float ts = red[0] + red[1] + red[2] + red[3];
    float tq = red[4] + red[5] + red[6] + red[7];
    float mean = ts * (1.f / 512.f);
    float var = tq * (1.f / 512.f) - mean * mean;
    float inv = rsqrtf(var + 1e-5f);
    float o0 = (v0 - mean) * inv * g[t] + bta[t];
    float o1 = (v1 - mean) * inv * g[t + 256] + bta[t + 256];
    outF[aoff + t] = o0;
    outF[aoff + t + 256] = o1;
    if (outB) { outB[aoff + t] = f2bf(o0); outB[aoff + t + 256] = f2bf(o1); }
}

extern "C" void kernel_launch(void* const* d_in, const int* in_sizes, int n_in,
                              void* d_out, int out_size, void* d_ws, size_t ws_size,
                              hipStream_t stream) {
    (void)in_sizes; (void)n_in; (void)out_size; (void)ws_size;
    const float* h       = (const float*)d_in[0];
    const float* arc_out = (const float*)d_in[1];
    const float* arc_in  = (const float*)d_in[2];
    const float* W_out_w = (const float*)d_in[4];
    const float* W_out_b = (const float*)d_in[5];
    const float* W_in_w  = (const float*)d_in[6];
    const float* W_in_b  = (const float*)d_in[7];
    const float* q_w  = (const float*)d_in[8];
    const float* q_b  = (const float*)d_in[9];
    const float* k_w  = (const float*)d_in[10];
    const float* k_b  = (const float*)d_in[11];
    const float* v_w  = (const float*)d_in[12];
    const float* v_b  = (const float*)d_in[13];
    const float* o_w  = (const float*)d_in[14];
    const float* o_b  = (const float*)d_in[15];
    const float* ln1_g = (const float*)d_in[16];
    const float* ln1_b = (const float*)d_in[17];
    const float* fc1_w = (const float*)d_in[18];
    const float* fc1_b = (const float*)d_in[19];
    const float* fc2_w = (const float*)d_in[20];
    const float* fc2_b = (const float*)d_in[21];
    const float* ln2_g = (const float*)d_in[22];
    const float* ln2_b = (const float*)d_in[23];
    float* out = (float*)d_out;

    char* wsb = (char*)d_ws;
    size_t off = 0;
    auto ALLOC = [&](size_t bytes) -> void* {
        void* ptr = wsb + off;
        off += (bytes + 255) & ~(size_t)255;
        return ptr;
    };
    unsigned short* WcatT = (unsigned short*)ALLOC((size_t)2560 * 512 * 2);
    unsigned short* W2to  = (unsigned short*)ALLOC(262144 * 2);
    unsigned short* W2ti  = (unsigned short*)ALLOC(262144 * 2);
    unsigned short* o_wT  = (unsigned short*)ALLOC(262144 * 2);
    unsigned short* v_wT  = (unsigned short*)ALLOC(262144 * 2);
    unsigned short* fc1T  = (unsigned short*)ALLOC((size_t)2048 * 512 * 2);
    unsigned short* fc2T  = (unsigned short*)ALLOC((size_t)512 * 2048 * 2);
    float* kwT   = (float*)ALLOC(262144 * 4);
    float* bias1 = (float*)ALLOC(2560 * 4);
    unsigned short* Qm = (unsigned short*)ALLOC(262144 * 2);
    float* QWcat = (float*)ALLOC((size_t)512 * 2560 * 4);
    unsigned short* pbuf = (unsigned short*)ALLOC((size_t)NTOK * 8 * 512 * 2);
    float* cbuf = (float*)ALLOC(NTOK * 8 * 4);
    unsigned short* Ubuf = (unsigned short*)ALLOC((size_t)NM * 512 * 2);
    float* Wsum = (float*)ALLOC((size_t)NTOK * 8 * 512 * 4);
    unsigned short* Waccb = (unsigned short*)ALLOC((size_t)NTOK * 8 * 512 * 2);
    unsigned short* tmpb  = (unsigned short*)ALLOC(262144 * 2);
    float* attsum = (float*)ALLOC(262144 * 4);
    float* x1  = (float*)ALLOC(262144 * 4);
    unsigned short* x1b = (unsigned short*)ALLOC(262144 * 2);
    unsigned short* ybb = (unsigned short*)ALLOC((size_t)NTOK * 2048 * 2);
    float* zparts = (float*)ALLOC((size_t)4 * 262144 * 4);

    k_prep<<<2058, 256, 0, stream>>>(h, Qm, k_w, kwT, W_out_b, W_in_b, q_b, bias1);

    // merged weight transposes (fp32 -> bf16 N x K)
    {
        TRJobs js = {};
        auto SET = [&](int i, const float* s, int sld, unsigned short* d, int dld,
                       float sc, int tiles, int tcols) {
            js.j[i] = TRJob{s, d, sld, dld, tcols, sc};
            js.start[i + 1] = js.start[i] + tiles;
        };
        js.start[0] = 0;
        SET(0,  W_out_w,              512, WcatT,              512, 1.f,    64, 8);
        SET(1,  W_out_w + 1024 * 512, 512, WcatT + 512 * 512,  512, 1.f,    64, 8);
        SET(2,  W_in_w,               512, WcatT + 1024 * 512, 512, 1.f,    64, 8);
        SET(3,  W_in_w + 1024 * 512,  512, WcatT + 1536 * 512, 512, 1.f,    64, 8);
        SET(4,  q_w,                  512, WcatT + 2048 * 512, 512, 0.125f, 64, 8);
        SET(5,  W_out_w + 512 * 512,  512, W2to,               512, 1.f,    64, 8);
        SET(6,  W_in_w + 512 * 512,   512, W2ti,               512, 1.f,    64, 8);
        SET(7,  o_w,                  512, o_wT,               512, 1.f,    64, 8);
        SET(8,  v_w,                  512, v_wT,               512, 1.f,    64, 8);
        SET(9,  fc1_w,               2048, fc1T,               512, 1.f,   256, 32);
        SET(10, fc2_w,                512, fc2T,              2048, 1.f,   256, 8);
        k_trN<<<js.start[11], 256, 0, stream>>>(js);
    }

    // batched Q-side projections: QWcat = Qm @ [W1o|W3o|W1i|W3i|q*.125] + bias1
    {
        MMP m = {};
        m.A = Qm; m.lda = 512; m.Bt = WcatT; m.ldb = 512;
        m.bias = bias1; m.biasScale = 1.f;
        m.outF = QWcat; m.ldo = 2560; m.K = 512;
        k_mm<<<dim3(8, 40), 256, 0, stream>>>(m);
    }
    k_prep2<<<dim3(64, 2), 256, 0, stream>>>(QWcat + 2048, 2560, kwT, k_b, pbuf, cbuf);

    for (int arc = 0; arc < 2; ++arc) {
        const float* arcp = (arc == 0) ? arc_out : arc_in;
        const unsigned short* w2 = (arc == 0) ? W2to : W2ti;
        const float* fixedM = (arc == 0) ? QWcat + 0    : QWcat + 1536;  // QW1o : QW3i
        const float* rowM   = (arc == 0) ? QWcat + 512  : QWcat + 1024;  // QW3o : QW1i
        k_midU<<<2048, 256, 0, stream>>>(arcp, w2, fixedM, 2560, rowM, 2560, Ubuf);
        k_att2<<<512, 256, 0, stream>>>(Ubuf, pbuf, cbuf, Wsum, Waccb, arc);
    }

    // Linear post-attention, summed over arcs:
    // att_out+att_in = ((Wacc0+Wacc1)@v_w per-head + 2*v_b)@o_w + 2*o_b
    {
        MMP m = {};
        m.A = Waccb; m.lda = 4096; m.aOffPerN64 = 512;
        m.Bt = v_wT; m.ldb = 512;
        m.bias = v_b; m.biasScale = 2.f;
        m.outB = tmpb; m.ldo = 512; m.K = 512;
        k_mm<<<dim3(8, 8), 256, 0, stream>>>(m);
    }
    {
        MMP m = {};
        m.A = tmpb; m.lda = 512; m.Bt = o_wT; m.ldb = 512;
        m.bias = o_b; m.biasScale = 2.f;
        m.outF = attsum; m.ldo = 512; m.K = 512;
        k_mm<<<dim3(8, 8), 256, 0, stream>>>(m);
    }

    k_ln<<<512, 256, 0, stream>>>(h, attsum, 1, nullptr, nullptr, ln1_g, ln1_b, x1, x1b);

    {
        MMP m = {};
        m.A = x1b; m.lda = 512; m.Bt = fc1T; m.ldb = 512;
        m.bias = fc1_b; m.biasScale = 1.f;
        m.relu = 1; m.outB = ybb; m.ldo = 2048; m.K = 512;
        k_mm<<<dim3(8, 32), 256, 0, stream>>>(m);
    }
    {
        MMP m = {};
        m.A = ybb; m.lda = 2048; m.Bt = fc2T; m.ldb = 2048;
        m.outF = zparts; m.ldo = 512; m.K = 512;
        m.zKOff = 512; m.zOutOff = 262144;
        k_mm<<<dim3(8, 8, 4), 256, 0, stream>>>(m);
    }
    k_ln<<<512, 256, 0, stream>>>(x1, nullptr, 0, zparts, fc2_b, ln2_g, ln2_b, out, nullptr);
}